// Round 1
// 255.886 us; speedup vs baseline: 1.0960x; 1.0960x over previous
//
#include <hip/hip_runtime.h>
#include <hip/hip_bf16.h>

// GAT-style graph attention. N=50000, E=600000, FEAT=128, H=8, D=16.
// R10: fill-path restructure. R9's fill_kernel was 44 µs with WRITE_SIZE=43MB:
//      the __builtin_nontemporal_store 4B scatter wrote one partial HBM line
//      per edge (16x write amplification, ~1 TB/s effective). Changes:
//      (a) plain cached store for the rec scatter — rec is 2.4MB, L2
//          write-allocates and merges the ~16 stores/line, L3 merges XCD
//          partials; (b) the CSR rank is captured from prep's EXISTING
//          histogram atomicAdd return value (coalesced rank[e] stream), so
//      fill has no atomics at all and cursor/scan3-cursor-write are gone.
//      Keeps: shfl-free sumexp (lane=(edge-octet,head), K-slice in regs,
//      in-lane 16-dot, coalesced Q loads, exp once), bf16 wraw.

#define FEAT 128
#define NHEAD 8
#define NPAD 50048   // N rounded up to multiple of 64

typedef __attribute__((ext_vector_type(8))) short bf16x8;
typedef __attribute__((ext_vector_type(4))) float f32x4;

__device__ __forceinline__ unsigned short f2bf(float f) {
    unsigned u = __float_as_uint(f);
    u += 0x7fffu + ((u >> 16) & 1u);
    return (unsigned short)(u >> 16);
}
__device__ __forceinline__ float bf2f_lo(unsigned u) { return __uint_as_float(u << 16); }
__device__ __forceinline__ float bf2f_hi(unsigned u) { return __uint_as_float(u & 0xffff0000u); }
__device__ __forceinline__ float bfw(unsigned short u) { return __uint_as_float((unsigned)u << 16); }

// ---- fused prep: dest histogram (+rank capture) | convert_x | convert_w ----
__global__ __launch_bounds__(256) void prep_kernel(
    const int* __restrict__ dsts, int* __restrict__ counts, int* __restrict__ rank,
    const float* __restrict__ X, unsigned short* __restrict__ Xb, int total8,
    const float* __restrict__ Wq, const float* __restrict__ Wk,
    const float* __restrict__ Wv, const float* __restrict__ Wo,
    unsigned short* __restrict__ Wb,
    int E, int histBlocks, int convxBlocks)
{
    int b = blockIdx.x;
    if (b < histBlocks) {
        int e = b * 256 + threadIdx.x;
        if (e < E) rank[e] = atomicAdd(counts + dsts[e], 1);
        return;
    }
    b -= histBlocks;
    if (b < convxBlocks) {
        int i = b * 256 + threadIdx.x;
        if (i >= total8) return;
        const float4* xp = (const float4*)X + (size_t)i * 2;
        float4 x0 = xp[0], x1 = xp[1];
        uint4 o;
        o.x = (unsigned)f2bf(x0.x) | ((unsigned)f2bf(x0.y) << 16);
        o.y = (unsigned)f2bf(x0.z) | ((unsigned)f2bf(x0.w) << 16);
        o.z = (unsigned)f2bf(x1.x) | ((unsigned)f2bf(x1.y) << 16);
        o.w = (unsigned)f2bf(x1.z) | ((unsigned)f2bf(x1.w) << 16);
        ((uint4*)Xb)[i] = o;
        return;
    }
    b -= convxBlocks;
    int i = b * 256 + threadIdx.x;
    if (i >= 4 * 2048) return;
    int mat = i >> 11, idx = i & 2047;
    const float* W = (mat == 0) ? Wq : (mat == 1) ? Wk : (mat == 2) ? Wv : Wo;
    const float4* xp = (const float4*)W + (size_t)idx * 2;
    float4 x0 = xp[0], x1 = xp[1];
    uint4 o;
    o.x = (unsigned)f2bf(x0.x) | ((unsigned)f2bf(x0.y) << 16);
    o.y = (unsigned)f2bf(x0.z) | ((unsigned)f2bf(x0.w) << 16);
    o.z = (unsigned)f2bf(x1.x) | ((unsigned)f2bf(x1.y) << 16);
    o.w = (unsigned)f2bf(x1.z) | ((unsigned)f2bf(x1.w) << 16);
    ((uint4*)(Wb + (size_t)mat * 16384))[idx] = o;
}

// ---- exclusive scan over N dest-counts ----
__global__ __launch_bounds__(256) void scan1_kernel(
    const int* __restrict__ counts, int* __restrict__ offsets,
    int* __restrict__ blocksums, int NT)
{
    __shared__ int buf[256];
    int t = threadIdx.x, i = blockIdx.x * 256 + t;
    int v = (i < NT) ? counts[i] : 0;
    buf[t] = v; __syncthreads();
    int x = v;
    #pragma unroll
    for (int off = 1; off < 256; off <<= 1) {
        int y = (t >= off) ? buf[t - off] : 0;
        __syncthreads();
        x += y; buf[t] = x;
        __syncthreads();
    }
    if (i < NT) offsets[i] = x - v;
    if (t == 255) blocksums[blockIdx.x] = x;
}

__global__ __launch_bounds__(256) void scan2_kernel(
    int* __restrict__ blocksums, int* __restrict__ blockoffs, int NB)
{
    __shared__ int buf[256];
    int t = threadIdx.x;
    int v = (t < NB) ? blocksums[t] : 0;
    buf[t] = v; __syncthreads();
    int x = v;
    #pragma unroll
    for (int off = 1; off < 256; off <<= 1) {
        int y = (t >= off) ? buf[t - off] : 0;
        __syncthreads();
        x += y; buf[t] = x;
        __syncthreads();
    }
    if (t < NB) blockoffs[t] = x - v;
}

__global__ __launch_bounds__(256) void scan3_kernel(
    int* __restrict__ offsets, const int* __restrict__ blockoffs, int NT)
{
    int i = blockIdx.x * 256 + threadIdx.x;
    if (i < NT) offsets[i] += blockoffs[blockIdx.x];
}

// ---- fill dest-CSR: pure scatter, no atomics, cached stores ----
__global__ __launch_bounds__(256) void fill_kernel(
    const int* __restrict__ srcs, const int* __restrict__ dsts,
    const int* __restrict__ rank, const int* __restrict__ offsets,
    int* __restrict__ rec, int E)
{
    int e = blockIdx.x * 256 + threadIdx.x;
    if (e < E) {
        int s = srcs[e], d = dsts[e];
        rec[offsets[d] + rank[e]] = s;
    }
}

// ---- QKV MFMA GEMM: wave owns 32-col strip, B frags persistent in regs ----
__global__ __launch_bounds__(256) void qkv_mfma_kernel(
    const unsigned short* __restrict__ Xb, const unsigned short* __restrict__ Wb,
    const float* __restrict__ bq, const float* __restrict__ bk, const float* __restrict__ bv,
    unsigned short* __restrict__ Q, unsigned short* __restrict__ K,
    unsigned short* __restrict__ V, int N, int numTiles)
{
    const int lane = threadIdx.x & 63;
    const int wave = threadIdx.x >> 6;
    const int m = lane & 15, quad = lane >> 4;
    const int colbase = wave * 32;

    bf16x8 bfr[3][2][4];
    #pragma unroll
    for (int mat = 0; mat < 3; mat++)
        #pragma unroll
        for (int ctl = 0; ctl < 2; ctl++) {
            const unsigned short* wrow =
                Wb + mat * 16384 + (size_t)(colbase + ctl * 16 + m) * FEAT + quad * 8;
            #pragma unroll
            for (int kc = 0; kc < 4; kc++)
                bfr[mat][ctl][kc] = *(const bf16x8*)(wrow + kc * 32);
        }

    const float* bias_p[3] = {bq, bk, bv};
    float bias[3][2];
    #pragma unroll
    for (int mat = 0; mat < 3; mat++)
        #pragma unroll
        for (int ctl = 0; ctl < 2; ctl++)
            bias[mat][ctl] = bias_p[mat][colbase + ctl * 16 + m];

    unsigned short* outp[3] = {Q, K, V};

    for (int tile = blockIdx.x; tile < numTiles; tile += gridDim.x) {
        const int row0 = tile * 16;
        const unsigned short* arow = Xb + (size_t)(row0 + m) * FEAT + quad * 8;
        bf16x8 a[4];
        #pragma unroll
        for (int kc = 0; kc < 4; kc++) a[kc] = *(const bf16x8*)(arow + kc * 32);
        f32x4 acc[3][2];
        #pragma unroll
        for (int mat = 0; mat < 3; mat++)
            #pragma unroll
            for (int ctl = 0; ctl < 2; ctl++) acc[mat][ctl] = (f32x4){0.f, 0.f, 0.f, 0.f};
        #pragma unroll
        for (int kc = 0; kc < 4; kc++)
            #pragma unroll
            for (int mat = 0; mat < 3; mat++)
                #pragma unroll
                for (int ctl = 0; ctl < 2; ctl++)
                    acc[mat][ctl] = __builtin_amdgcn_mfma_f32_16x16x32_bf16(
                        a[kc], bfr[mat][ctl][kc], acc[mat][ctl], 0, 0, 0);
        #pragma unroll
        for (int mat = 0; mat < 3; mat++)
            #pragma unroll
            for (int ctl = 0; ctl < 2; ctl++)
                #pragma unroll
                for (int reg = 0; reg < 4; reg++) {
                    int row = row0 + quad * 4 + reg;
                    if (row < N)
                        outp[mat][(size_t)row * FEAT + colbase + ctl * 16 + m] =
                            f2bf(acc[mat][ctl][reg] + bias[mat][ctl]);
                }
    }
}

// ---- sumexp: one wave per DEST node, shfl-free.
//      lane = (edge-octet j=lane>>3, head h=lane&7). K slice (16 f32) in
//      regs; per 8-edge chunk: two coalesced dwordx4 Q-slice loads, full
//      in-lane dot, exp once, contiguous bf16 wraw store, atomicAdd
//      segsum[src*8+h] (L2-resident). ----
__global__ __launch_bounds__(256) void sumexp_kernel(
    const int* __restrict__ offsets, const int* __restrict__ counts,
    const int* __restrict__ rec,
    const unsigned short* __restrict__ Q, const unsigned short* __restrict__ K,
    unsigned short* __restrict__ wrawb, float* __restrict__ segsum, int N)
{
    int node = blockIdx.x * 4 + (threadIdx.x >> 6);
    if (node >= N) return;
    int lane = threadIdx.x & 63;
    int j = lane >> 3, h = lane & 7;
    int start = offsets[node], deg = counts[node];
    if (deg == 0) return;

    float kf[16];
    {
        const unsigned* kp = (const unsigned*)(K + (size_t)node * FEAT + h * 16);
        #pragma unroll
        for (int i = 0; i < 8; i++) {
            unsigned u = kp[i];
            kf[2 * i]     = bf2f_lo(u);
            kf[2 * i + 1] = bf2f_hi(u);
        }
    }

    for (int j0 = 0; j0 < deg; j0 += 8) {
        int jj = j0 + j;
        bool act = jj < deg;
        int pos = start + (act ? jj : j0);
        int s = rec[pos];
        const unsigned* qp = (const unsigned*)(Q + (size_t)s * FEAT + h * 16);
        uint4 qa = *(const uint4*)qp;
        uint4 qb = *(const uint4*)(qp + 4);
        float p;
        p  = bf2f_lo(qa.x) * kf[0]  + bf2f_hi(qa.x) * kf[1];
        p += bf2f_lo(qa.y) * kf[2]  + bf2f_hi(qa.y) * kf[3];
        p += bf2f_lo(qa.z) * kf[4]  + bf2f_hi(qa.z) * kf[5];
        p += bf2f_lo(qa.w) * kf[6]  + bf2f_hi(qa.w) * kf[7];
        p += bf2f_lo(qb.x) * kf[8]  + bf2f_hi(qb.x) * kf[9];
        p += bf2f_lo(qb.y) * kf[10] + bf2f_hi(qb.y) * kf[11];
        p += bf2f_lo(qb.z) * kf[12] + bf2f_hi(qb.z) * kf[13];
        p += bf2f_lo(qb.w) * kf[14] + bf2f_hi(qb.w) * kf[15];
        float w = __expf(p * 0.25f);
        if (act) {
            wrawb[(size_t)(start + j0) * NHEAD + lane] = f2bf(w);
            atomicAdd(segsum + (size_t)s * NHEAD + h, w);
        }
    }
}

// ---- reciprocal of segsum ----
__global__ __launch_bounds__(256) void recip_kernel(float* __restrict__ segsum, int n)
{
    int i = blockIdx.x * 256 + threadIdx.x;
    if (i < n) segsum[i] = 1.0f / segsum[i];
}

// ---- gather: one wave per dest node; bf16 V rows, bf16 wraw,
//      rsegsum[src] normalization, 4x-unrolled random V-row loads ----
__global__ __launch_bounds__(256) void gather_kernel(
    const int* __restrict__ offsets, const int* __restrict__ counts,
    const int* __restrict__ rec, const unsigned short* __restrict__ wrawb,
    const float* __restrict__ rsegsum, const unsigned short* __restrict__ V,
    unsigned short* __restrict__ agg, int N)
{
    int node = blockIdx.x * 4 + (threadIdx.x >> 6);
    if (node >= N) return;
    int lane = threadIdx.x & 63;
    int h = lane >> 3;
    int start = offsets[node], deg = counts[node];
    float ax = 0.f, ay = 0.f;
    int j = 0;
    for (; j + 4 <= deg; j += 4) {
        int p = start + j;
        int s0 = rec[p], s1 = rec[p + 1];
        int s2 = rec[p + 2], s3 = rec[p + 3];
        float w0 = bfw(wrawb[(size_t)(p + 0) * NHEAD + h]) * rsegsum[(size_t)s0 * NHEAD + h];
        float w1 = bfw(wrawb[(size_t)(p + 1) * NHEAD + h]) * rsegsum[(size_t)s1 * NHEAD + h];
        float w2 = bfw(wrawb[(size_t)(p + 2) * NHEAD + h]) * rsegsum[(size_t)s2 * NHEAD + h];
        float w3 = bfw(wrawb[(size_t)(p + 3) * NHEAD + h]) * rsegsum[(size_t)s3 * NHEAD + h];
        unsigned v0 = *(const unsigned*)(V + (size_t)s0 * FEAT + lane * 2);
        unsigned v1 = *(const unsigned*)(V + (size_t)s1 * FEAT + lane * 2);
        unsigned v2 = *(const unsigned*)(V + (size_t)s2 * FEAT + lane * 2);
        unsigned v3 = *(const unsigned*)(V + (size_t)s3 * FEAT + lane * 2);
        ax += w0 * bf2f_lo(v0) + w1 * bf2f_lo(v1) + w2 * bf2f_lo(v2) + w3 * bf2f_lo(v3);
        ay += w0 * bf2f_hi(v0) + w1 * bf2f_hi(v1) + w2 * bf2f_hi(v2) + w3 * bf2f_hi(v3);
    }
    for (; j < deg; j++) {
        int p = start + j;
        int s = rec[p];
        float w = bfw(wrawb[(size_t)p * NHEAD + h]) * rsegsum[(size_t)s * NHEAD + h];
        unsigned v = *(const unsigned*)(V + (size_t)s * FEAT + lane * 2);
        ax += w * bf2f_lo(v);
        ay += w * bf2f_hi(v);
    }
    unsigned o = (unsigned)f2bf(ax) | ((unsigned)f2bf(ay) << 16);
    *(unsigned*)(agg + (size_t)node * FEAT + lane * 2) = o;
}

// ---- out MFMA GEMM: persistent-B structure, 1 matrix, f32 out ----
__global__ __launch_bounds__(256) void out_mfma_kernel(
    const unsigned short* __restrict__ Ab, const unsigned short* __restrict__ Wob,
    const float* __restrict__ bo, float* __restrict__ out, int N, int numTiles)
{
    const int lane = threadIdx.x & 63;
    const int wave = threadIdx.x >> 6;
    const int m = lane & 15, quad = lane >> 4;
    const int colbase = wave * 32;

    bf16x8 bfr[2][4];
    #pragma unroll
    for (int ctl = 0; ctl < 2; ctl++) {
        const unsigned short* wrow = Wob + (size_t)(colbase + ctl * 16 + m) * FEAT + quad * 8;
        #pragma unroll
        for (int kc = 0; kc < 4; kc++)
            bfr[ctl][kc] = *(const bf16x8*)(wrow + kc * 32);
    }
    float bias[2];
    #pragma unroll
    for (int ctl = 0; ctl < 2; ctl++) bias[ctl] = bo[colbase + ctl * 16 + m];

    for (int tile = blockIdx.x; tile < numTiles; tile += gridDim.x) {
        const int row0 = tile * 16;
        const unsigned short* arow = Ab + (size_t)(row0 + m) * FEAT + quad * 8;
        bf16x8 a[4];
        #pragma unroll
        for (int kc = 0; kc < 4; kc++) a[kc] = *(const bf16x8*)(arow + kc * 32);
        f32x4 acc[2];
        #pragma unroll
        for (int ctl = 0; ctl < 2; ctl++) acc[ctl] = (f32x4){0.f, 0.f, 0.f, 0.f};
        #pragma unroll
        for (int kc = 0; kc < 4; kc++)
            #pragma unroll
            for (int ctl = 0; ctl < 2; ctl++)
                acc[ctl] = __builtin_amdgcn_mfma_f32_16x16x32_bf16(
                    a[kc], bfr[ctl][kc], acc[ctl], 0, 0, 0);
        #pragma unroll
        for (int ctl = 0; ctl < 2; ctl++)
            #pragma unroll
            for (int reg = 0; reg < 4; reg++) {
                int row = row0 + quad * 4 + reg;
                if (row < N)
                    out[(size_t)row * FEAT + colbase + ctl * 16 + m] = acc[ctl][reg] + bias[ctl];
            }
    }
}

extern "C" void kernel_launch(void* const* d_in, const int* in_sizes, int n_in,
                              void* d_out, int out_size, void* d_ws, size_t ws_size,
                              hipStream_t stream) {
    const float* X  = (const float*)d_in[0];
    const int*   ei = (const int*)d_in[1];
    const float* Wq = (const float*)d_in[2];
    const float* bq = (const float*)d_in[3];
    const float* Wk = (const float*)d_in[4];
    const float* bk = (const float*)d_in[5];
    const float* Wv = (const float*)d_in[6];
    const float* bv = (const float*)d_in[7];
    const float* Wo = (const float*)d_in[8];
    const float* bo = (const float*)d_in[9];
    float* out = (float*)d_out;

    const int N = in_sizes[0] / FEAT;        // 50000
    const int E = in_sizes[1] / 2;           // 600000
    const int* srcs = ei;
    const int* dsts = ei + E;
    const size_t NF2 = (size_t)NPAD * FEAT * 2;

    char* w = (char*)d_ws;
    unsigned short* Xb = (unsigned short*)w;  w += NF2;       // also Ab (after qkv)
    unsigned short* Qb = (unsigned short*)w;  w += NF2;
    unsigned short* Kb = (unsigned short*)w;  w += NF2;
    unsigned short* Vb = (unsigned short*)w;  w += NF2;
    unsigned short* Wb = (unsigned short*)w;  w += (size_t)4 * 16384 * 2;
    unsigned short* wrawb = (unsigned short*)w; w += (size_t)E * NHEAD * 2;  // bf16
    float* segsum      = (float*)w;           w += (size_t)N * NHEAD * 4;  // zeroed
    int* counts        = (int*)w;             w += (size_t)N * 4;          // zeroed (contig)
    int* offsets       = (int*)w;             w += (size_t)N * 4;
    int* blocksums     = (int*)w;             w += 256 * 4;
    int* blockoffs     = (int*)w;             w += 256 * 4;
    int* rec           = (int*)w;             w += (size_t)E * 4;
    int* rank          = (int*)w;             w += (size_t)E * 4;

    unsigned short* Ab = Xb;   // Xb dead after qkv

    // zero segsum + counts (contiguous)
    hipMemsetAsync(segsum, 0, ((size_t)N * NHEAD + N) * sizeof(float), stream);

    int e_blocks = (E + 255) / 256;          // 2344
    int x8 = N * FEAT / 8;
    int convx_blocks = (x8 + 255) / 256;     // 3125
    int convw_blocks = 32;
    prep_kernel<<<e_blocks + convx_blocks + convw_blocks, 256, 0, stream>>>(
        dsts, counts, rank, X, Xb, x8, Wq, Wk, Wv, Wo, Wb,
        E, e_blocks, convx_blocks);

    int NB = (N + 255) / 256;   // 196
    scan1_kernel<<<NB, 256, 0, stream>>>(counts, offsets, blocksums, N);
    scan2_kernel<<<1, 256, 0, stream>>>(blocksums, blockoffs, NB);
    scan3_kernel<<<NB, 256, 0, stream>>>(offsets, blockoffs, N);

    fill_kernel<<<e_blocks, 256, 0, stream>>>(srcs, dsts, rank, offsets, rec, E);

    int numTiles = NPAD / 16;   // 3128
    qkv_mfma_kernel<<<782, 256, 0, stream>>>(Xb, Wb, bq, bk, bv, Qb, Kb, Vb, N, numTiles);

    int node_blocks = (N + 3) / 4;
    sumexp_kernel<<<node_blocks, 256, 0, stream>>>(
        offsets, counts, rec, Qb, Kb, wrawb, segsum, N);

    recip_kernel<<<(N * NHEAD + 255) / 256, 256, 0, stream>>>(segsum, N * NHEAD);

    gather_kernel<<<node_blocks, 256, 0, stream>>>(
        offsets, counts, rec, wrawb, segsum, Vb, Ab, N);

    out_mfma_kernel<<<782, 256, 0, stream>>>(Ab, Wb + 3 * 16384, bo, out, N, numTiles);
}

// Round 2
// 250.946 us; speedup vs baseline: 1.1176x; 1.0197x over previous
//
#include <hip/hip_runtime.h>
#include <hip/hip_bf16.h>

// GAT-style graph attention. N=50000, E=600000, FEAT=128, H=8, D=16.
// R11: (a) fill fused into qkv_mfma as a block-partitioned combined kernel
//      (fill is latency-bound scatter, qkv is MFMA-bound — disjoint pipes,
//      fill hides under the GEMM); (b) V pre-scaled by 1/segsum per (src,h)
//      right after sumexp (legal: softmax denom is per-(src,head), exactly a
//      V row-slice) — deletes the per-edge random rsegsum gather from
//      gather_kernel and absorbs recip_kernel. 11 -> 10 dispatches.
//      Keeps: rank-from-histogram CSR fill (R10), shfl-free sumexp, bf16 wraw.

#define FEAT 128
#define NHEAD 8
#define NPAD 50048   // N rounded up to multiple of 64

typedef __attribute__((ext_vector_type(8))) short bf16x8;
typedef __attribute__((ext_vector_type(4))) float f32x4;

__device__ __forceinline__ unsigned short f2bf(float f) {
    unsigned u = __float_as_uint(f);
    u += 0x7fffu + ((u >> 16) & 1u);
    return (unsigned short)(u >> 16);
}
__device__ __forceinline__ float bf2f_lo(unsigned u) { return __uint_as_float(u << 16); }
__device__ __forceinline__ float bf2f_hi(unsigned u) { return __uint_as_float(u & 0xffff0000u); }
__device__ __forceinline__ float bfw(unsigned short u) { return __uint_as_float((unsigned)u << 16); }

// ---- fused prep: dest histogram (+rank capture) | convert_x | convert_w ----
__global__ __launch_bounds__(256) void prep_kernel(
    const int* __restrict__ dsts, int* __restrict__ counts, int* __restrict__ rank,
    const float* __restrict__ X, unsigned short* __restrict__ Xb, int total8,
    const float* __restrict__ Wq, const float* __restrict__ Wk,
    const float* __restrict__ Wv, const float* __restrict__ Wo,
    unsigned short* __restrict__ Wb,
    int E, int histBlocks, int convxBlocks)
{
    int b = blockIdx.x;
    if (b < histBlocks) {
        int e = b * 256 + threadIdx.x;
        if (e < E) rank[e] = atomicAdd(counts + dsts[e], 1);
        return;
    }
    b -= histBlocks;
    if (b < convxBlocks) {
        int i = b * 256 + threadIdx.x;
        if (i >= total8) return;
        const float4* xp = (const float4*)X + (size_t)i * 2;
        float4 x0 = xp[0], x1 = xp[1];
        uint4 o;
        o.x = (unsigned)f2bf(x0.x) | ((unsigned)f2bf(x0.y) << 16);
        o.y = (unsigned)f2bf(x0.z) | ((unsigned)f2bf(x0.w) << 16);
        o.z = (unsigned)f2bf(x1.x) | ((unsigned)f2bf(x1.y) << 16);
        o.w = (unsigned)f2bf(x1.z) | ((unsigned)f2bf(x1.w) << 16);
        ((uint4*)Xb)[i] = o;
        return;
    }
    b -= convxBlocks;
    int i = b * 256 + threadIdx.x;
    if (i >= 4 * 2048) return;
    int mat = i >> 11, idx = i & 2047;
    const float* W = (mat == 0) ? Wq : (mat == 1) ? Wk : (mat == 2) ? Wv : Wo;
    const float4* xp = (const float4*)W + (size_t)idx * 2;
    float4 x0 = xp[0], x1 = xp[1];
    uint4 o;
    o.x = (unsigned)f2bf(x0.x) | ((unsigned)f2bf(x0.y) << 16);
    o.y = (unsigned)f2bf(x0.z) | ((unsigned)f2bf(x0.w) << 16);
    o.z = (unsigned)f2bf(x1.x) | ((unsigned)f2bf(x1.y) << 16);
    o.w = (unsigned)f2bf(x1.z) | ((unsigned)f2bf(x1.w) << 16);
    ((uint4*)(Wb + (size_t)mat * 16384))[idx] = o;
}

// ---- exclusive scan over N dest-counts ----
__global__ __launch_bounds__(256) void scan1_kernel(
    const int* __restrict__ counts, int* __restrict__ offsets,
    int* __restrict__ blocksums, int NT)
{
    __shared__ int buf[256];
    int t = threadIdx.x, i = blockIdx.x * 256 + t;
    int v = (i < NT) ? counts[i] : 0;
    buf[t] = v; __syncthreads();
    int x = v;
    #pragma unroll
    for (int off = 1; off < 256; off <<= 1) {
        int y = (t >= off) ? buf[t - off] : 0;
        __syncthreads();
        x += y; buf[t] = x;
        __syncthreads();
    }
    if (i < NT) offsets[i] = x - v;
    if (t == 255) blocksums[blockIdx.x] = x;
}

__global__ __launch_bounds__(256) void scan2_kernel(
    int* __restrict__ blocksums, int* __restrict__ blockoffs, int NB)
{
    __shared__ int buf[256];
    int t = threadIdx.x;
    int v = (t < NB) ? blocksums[t] : 0;
    buf[t] = v; __syncthreads();
    int x = v;
    #pragma unroll
    for (int off = 1; off < 256; off <<= 1) {
        int y = (t >= off) ? buf[t - off] : 0;
        __syncthreads();
        x += y; buf[t] = x;
        __syncthreads();
    }
    if (t < NB) blockoffs[t] = x - v;
}

__global__ __launch_bounds__(256) void scan3_kernel(
    int* __restrict__ offsets, const int* __restrict__ blockoffs, int NT)
{
    int i = blockIdx.x * 256 + threadIdx.x;
    if (i < NT) offsets[i] += blockoffs[blockIdx.x];
}

// ---- combined: QKV MFMA GEMM (blocks [0,qkvBlocks)) + dest-CSR fill
//      (blocks [qkvBlocks, qkvBlocks+fillBlocks)). Fill is a pure
//      latency-bound scatter (no atomics) that hides under the GEMM. ----
__global__ __launch_bounds__(256) void fillqkv_kernel(
    // qkv part
    const unsigned short* __restrict__ Xb, const unsigned short* __restrict__ Wb,
    const float* __restrict__ bq, const float* __restrict__ bk, const float* __restrict__ bv,
    unsigned short* __restrict__ Q, unsigned short* __restrict__ K,
    unsigned short* __restrict__ V, int N, int numTiles, int qkvBlocks,
    // fill part
    const int* __restrict__ srcs, const int* __restrict__ dsts,
    const int* __restrict__ rank, const int* __restrict__ offsets,
    int* __restrict__ rec, int E)
{
    if (blockIdx.x >= qkvBlocks) {
        int e = (blockIdx.x - qkvBlocks) * 256 + threadIdx.x;
        if (e < E) {
            int s = srcs[e], d = dsts[e];
            rec[offsets[d] + rank[e]] = s;
        }
        return;
    }

    const int lane = threadIdx.x & 63;
    const int wave = threadIdx.x >> 6;
    const int m = lane & 15, quad = lane >> 4;
    const int colbase = wave * 32;

    bf16x8 bfr[3][2][4];
    #pragma unroll
    for (int mat = 0; mat < 3; mat++)
        #pragma unroll
        for (int ctl = 0; ctl < 2; ctl++) {
            const unsigned short* wrow =
                Wb + mat * 16384 + (size_t)(colbase + ctl * 16 + m) * FEAT + quad * 8;
            #pragma unroll
            for (int kc = 0; kc < 4; kc++)
                bfr[mat][ctl][kc] = *(const bf16x8*)(wrow + kc * 32);
        }

    const float* bias_p[3] = {bq, bk, bv};
    float bias[3][2];
    #pragma unroll
    for (int mat = 0; mat < 3; mat++)
        #pragma unroll
        for (int ctl = 0; ctl < 2; ctl++)
            bias[mat][ctl] = bias_p[mat][colbase + ctl * 16 + m];

    unsigned short* outp[3] = {Q, K, V};

    for (int tile = blockIdx.x; tile < numTiles; tile += qkvBlocks) {
        const int row0 = tile * 16;
        const unsigned short* arow = Xb + (size_t)(row0 + m) * FEAT + quad * 8;
        bf16x8 a[4];
        #pragma unroll
        for (int kc = 0; kc < 4; kc++) a[kc] = *(const bf16x8*)(arow + kc * 32);
        f32x4 acc[3][2];
        #pragma unroll
        for (int mat = 0; mat < 3; mat++)
            #pragma unroll
            for (int ctl = 0; ctl < 2; ctl++) acc[mat][ctl] = (f32x4){0.f, 0.f, 0.f, 0.f};
        #pragma unroll
        for (int kc = 0; kc < 4; kc++)
            #pragma unroll
            for (int mat = 0; mat < 3; mat++)
                #pragma unroll
                for (int ctl = 0; ctl < 2; ctl++)
                    acc[mat][ctl] = __builtin_amdgcn_mfma_f32_16x16x32_bf16(
                        a[kc], bfr[mat][ctl][kc], acc[mat][ctl], 0, 0, 0);
        #pragma unroll
        for (int mat = 0; mat < 3; mat++)
            #pragma unroll
            for (int ctl = 0; ctl < 2; ctl++)
                #pragma unroll
                for (int reg = 0; reg < 4; reg++) {
                    int row = row0 + quad * 4 + reg;
                    if (row < N)
                        outp[mat][(size_t)row * FEAT + colbase + ctl * 16 + m] =
                            f2bf(acc[mat][ctl][reg] + bias[mat][ctl]);
                }
    }
}

// ---- sumexp: one wave per DEST node, shfl-free.
//      lane = (edge-octet j=lane>>3, head h=lane&7). K slice (16 f32) in
//      regs; per 8-edge chunk: two coalesced dwordx4 Q-slice loads, full
//      in-lane dot, exp once, contiguous bf16 wraw store, atomicAdd
//      segsum[src*8+h] (L2-resident). ----
__global__ __launch_bounds__(256) void sumexp_kernel(
    const int* __restrict__ offsets, const int* __restrict__ counts,
    const int* __restrict__ rec,
    const unsigned short* __restrict__ Q, const unsigned short* __restrict__ K,
    unsigned short* __restrict__ wrawb, float* __restrict__ segsum, int N)
{
    int node = blockIdx.x * 4 + (threadIdx.x >> 6);
    if (node >= N) return;
    int lane = threadIdx.x & 63;
    int j = lane >> 3, h = lane & 7;
    int start = offsets[node], deg = counts[node];
    if (deg == 0) return;

    float kf[16];
    {
        const unsigned* kp = (const unsigned*)(K + (size_t)node * FEAT + h * 16);
        #pragma unroll
        for (int i = 0; i < 8; i++) {
            unsigned u = kp[i];
            kf[2 * i]     = bf2f_lo(u);
            kf[2 * i + 1] = bf2f_hi(u);
        }
    }

    for (int j0 = 0; j0 < deg; j0 += 8) {
        int jj = j0 + j;
        bool act = jj < deg;
        int pos = start + (act ? jj : j0);
        int s = rec[pos];
        const unsigned* qp = (const unsigned*)(Q + (size_t)s * FEAT + h * 16);
        uint4 qa = *(const uint4*)qp;
        uint4 qb = *(const uint4*)(qp + 4);
        float p;
        p  = bf2f_lo(qa.x) * kf[0]  + bf2f_hi(qa.x) * kf[1];
        p += bf2f_lo(qa.y) * kf[2]  + bf2f_hi(qa.y) * kf[3];
        p += bf2f_lo(qa.z) * kf[4]  + bf2f_hi(qa.z) * kf[5];
        p += bf2f_lo(qa.w) * kf[6]  + bf2f_hi(qa.w) * kf[7];
        p += bf2f_lo(qb.x) * kf[8]  + bf2f_hi(qb.x) * kf[9];
        p += bf2f_lo(qb.y) * kf[10] + bf2f_hi(qb.y) * kf[11];
        p += bf2f_lo(qb.z) * kf[12] + bf2f_hi(qb.z) * kf[13];
        p += bf2f_lo(qb.w) * kf[14] + bf2f_hi(qb.w) * kf[15];
        float w = __expf(p * 0.25f);
        if (act) {
            wrawb[(size_t)(start + j0) * NHEAD + lane] = f2bf(w);
            atomicAdd(segsum + (size_t)s * NHEAD + h, w);
        }
    }
}

// ---- scale V in place by 1/segsum per (node, head); absorbs recip.
//      One thread per 8 bf16 (uint4); 8 cols never straddle a head. ----
__global__ __launch_bounds__(256) void scalev_kernel(
    const float* __restrict__ segsum, unsigned short* __restrict__ V, int total16)
{
    int i = blockIdx.x * 256 + threadIdx.x;
    if (i >= total16) return;
    int s = i >> 4;
    int part = i & 15;           // which 8-col chunk of the 128-col row
    int h = part >> 1;
    float r = 1.0f / segsum[s * NHEAD + h];
    uint4* p = (uint4*)(V + (size_t)s * FEAT) + part;
    uint4 v = *p;
    uint4 o;
    o.x = (unsigned)f2bf(bf2f_lo(v.x) * r) | ((unsigned)f2bf(bf2f_hi(v.x) * r) << 16);
    o.y = (unsigned)f2bf(bf2f_lo(v.y) * r) | ((unsigned)f2bf(bf2f_hi(v.y) * r) << 16);
    o.z = (unsigned)f2bf(bf2f_lo(v.z) * r) | ((unsigned)f2bf(bf2f_hi(v.z) * r) << 16);
    o.w = (unsigned)f2bf(bf2f_lo(v.w) * r) | ((unsigned)f2bf(bf2f_hi(v.w) * r) << 16);
    *p = o;
}

// ---- gather: one wave per dest node; bf16 V' rows (pre-normalized),
//      bf16 wraw, 4x-unrolled random V-row loads ----
__global__ __launch_bounds__(256) void gather_kernel(
    const int* __restrict__ offsets, const int* __restrict__ counts,
    const int* __restrict__ rec, const unsigned short* __restrict__ wrawb,
    const unsigned short* __restrict__ V,
    unsigned short* __restrict__ agg, int N)
{
    int node = blockIdx.x * 4 + (threadIdx.x >> 6);
    if (node >= N) return;
    int lane = threadIdx.x & 63;
    int h = lane >> 3;
    int start = offsets[node], deg = counts[node];
    float ax = 0.f, ay = 0.f;
    int j = 0;
    for (; j + 4 <= deg; j += 4) {
        int p = start + j;
        int s0 = rec[p], s1 = rec[p + 1];
        int s2 = rec[p + 2], s3 = rec[p + 3];
        float w0 = bfw(wrawb[(size_t)(p + 0) * NHEAD + h]);
        float w1 = bfw(wrawb[(size_t)(p + 1) * NHEAD + h]);
        float w2 = bfw(wrawb[(size_t)(p + 2) * NHEAD + h]);
        float w3 = bfw(wrawb[(size_t)(p + 3) * NHEAD + h]);
        unsigned v0 = *(const unsigned*)(V + (size_t)s0 * FEAT + lane * 2);
        unsigned v1 = *(const unsigned*)(V + (size_t)s1 * FEAT + lane * 2);
        unsigned v2 = *(const unsigned*)(V + (size_t)s2 * FEAT + lane * 2);
        unsigned v3 = *(const unsigned*)(V + (size_t)s3 * FEAT + lane * 2);
        ax += w0 * bf2f_lo(v0) + w1 * bf2f_lo(v1) + w2 * bf2f_lo(v2) + w3 * bf2f_lo(v3);
        ay += w0 * bf2f_hi(v0) + w1 * bf2f_hi(v1) + w2 * bf2f_hi(v2) + w3 * bf2f_hi(v3);
    }
    for (; j < deg; j++) {
        int p = start + j;
        int s = rec[p];
        float w = bfw(wrawb[(size_t)p * NHEAD + h]);
        unsigned v = *(const unsigned*)(V + (size_t)s * FEAT + lane * 2);
        ax += w * bf2f_lo(v);
        ay += w * bf2f_hi(v);
    }
    unsigned o = (unsigned)f2bf(ax) | ((unsigned)f2bf(ay) << 16);
    *(unsigned*)(agg + (size_t)node * FEAT + lane * 2) = o;
}

// ---- out MFMA GEMM: persistent-B structure, 1 matrix, f32 out ----
__global__ __launch_bounds__(256) void out_mfma_kernel(
    const unsigned short* __restrict__ Ab, const unsigned short* __restrict__ Wob,
    const float* __restrict__ bo, float* __restrict__ out, int N, int numTiles)
{
    const int lane = threadIdx.x & 63;
    const int wave = threadIdx.x >> 6;
    const int m = lane & 15, quad = lane >> 4;
    const int colbase = wave * 32;

    bf16x8 bfr[2][4];
    #pragma unroll
    for (int ctl = 0; ctl < 2; ctl++) {
        const unsigned short* wrow = Wob + (size_t)(colbase + ctl * 16 + m) * FEAT + quad * 8;
        #pragma unroll
        for (int kc = 0; kc < 4; kc++)
            bfr[ctl][kc] = *(const bf16x8*)(wrow + kc * 32);
    }
    float bias[2];
    #pragma unroll
    for (int ctl = 0; ctl < 2; ctl++) bias[ctl] = bo[colbase + ctl * 16 + m];

    for (int tile = blockIdx.x; tile < numTiles; tile += gridDim.x) {
        const int row0 = tile * 16;
        const unsigned short* arow = Ab + (size_t)(row0 + m) * FEAT + quad * 8;
        bf16x8 a[4];
        #pragma unroll
        for (int kc = 0; kc < 4; kc++) a[kc] = *(const bf16x8*)(arow + kc * 32);
        f32x4 acc[2];
        #pragma unroll
        for (int ctl = 0; ctl < 2; ctl++) acc[ctl] = (f32x4){0.f, 0.f, 0.f, 0.f};
        #pragma unroll
        for (int kc = 0; kc < 4; kc++)
            #pragma unroll
            for (int ctl = 0; ctl < 2; ctl++)
                acc[ctl] = __builtin_amdgcn_mfma_f32_16x16x32_bf16(
                    a[kc], bfr[ctl][kc], acc[ctl], 0, 0, 0);
        #pragma unroll
        for (int ctl = 0; ctl < 2; ctl++)
            #pragma unroll
            for (int reg = 0; reg < 4; reg++) {
                int row = row0 + quad * 4 + reg;
                if (row < N)
                    out[(size_t)row * FEAT + colbase + ctl * 16 + m] = acc[ctl][reg] + bias[ctl];
            }
    }
}

extern "C" void kernel_launch(void* const* d_in, const int* in_sizes, int n_in,
                              void* d_out, int out_size, void* d_ws, size_t ws_size,
                              hipStream_t stream) {
    const float* X  = (const float*)d_in[0];
    const int*   ei = (const int*)d_in[1];
    const float* Wq = (const float*)d_in[2];
    const float* bq = (const float*)d_in[3];
    const float* Wk = (const float*)d_in[4];
    const float* bk = (const float*)d_in[5];
    const float* Wv = (const float*)d_in[6];
    const float* bv = (const float*)d_in[7];
    const float* Wo = (const float*)d_in[8];
    const float* bo = (const float*)d_in[9];
    float* out = (float*)d_out;

    const int N = in_sizes[0] / FEAT;        // 50000
    const int E = in_sizes[1] / 2;           // 600000
    const int* srcs = ei;
    const int* dsts = ei + E;
    const size_t NF2 = (size_t)NPAD * FEAT * 2;

    char* w = (char*)d_ws;
    unsigned short* Xb = (unsigned short*)w;  w += NF2;       // also Ab (after qkv)
    unsigned short* Qb = (unsigned short*)w;  w += NF2;
    unsigned short* Kb = (unsigned short*)w;  w += NF2;
    unsigned short* Vb = (unsigned short*)w;  w += NF2;
    unsigned short* Wb = (unsigned short*)w;  w += (size_t)4 * 16384 * 2;
    unsigned short* wrawb = (unsigned short*)w; w += (size_t)E * NHEAD * 2;  // bf16
    float* segsum      = (float*)w;           w += (size_t)N * NHEAD * 4;  // zeroed
    int* counts        = (int*)w;             w += (size_t)N * 4;          // zeroed (contig)
    int* offsets       = (int*)w;             w += (size_t)N * 4;
    int* blocksums     = (int*)w;             w += 256 * 4;
    int* blockoffs     = (int*)w;             w += 256 * 4;
    int* rec           = (int*)w;             w += (size_t)E * 4;
    int* rank          = (int*)w;             w += (size_t)E * 4;

    unsigned short* Ab = Xb;   // Xb dead after qkv

    // zero segsum + counts (contiguous)
    hipMemsetAsync(segsum, 0, ((size_t)N * NHEAD + N) * sizeof(float), stream);

    int e_blocks = (E + 255) / 256;          // 2344
    int x8 = N * FEAT / 8;
    int convx_blocks = (x8 + 255) / 256;     // 3125
    int convw_blocks = 32;
    prep_kernel<<<e_blocks + convx_blocks + convw_blocks, 256, 0, stream>>>(
        dsts, counts, rank, X, Xb, x8, Wq, Wk, Wv, Wo, Wb,
        E, e_blocks, convx_blocks);

    int NB = (N + 255) / 256;   // 196
    scan1_kernel<<<NB, 256, 0, stream>>>(counts, offsets, blocksums, N);
    scan2_kernel<<<1, 256, 0, stream>>>(blocksums, blockoffs, NB);
    scan3_kernel<<<NB, 256, 0, stream>>>(offsets, blockoffs, N);

    int numTiles = NPAD / 16;   // 3128
    int qkvBlocks = 782;
    fillqkv_kernel<<<qkvBlocks + e_blocks, 256, 0, stream>>>(
        Xb, Wb, bq, bk, bv, Qb, Kb, Vb, N, numTiles, qkvBlocks,
        srcs, dsts, rank, offsets, rec, E);

    int node_blocks = (N + 3) / 4;
    sumexp_kernel<<<node_blocks, 256, 0, stream>>>(
        offsets, counts, rec, Qb, Kb, wrawb, segsum, N);

    scalev_kernel<<<(N * 16 + 255) / 256, 256, 0, stream>>>(segsum, Vb, N * 16);

    gather_kernel<<<node_blocks, 256, 0, stream>>>(
        offsets, counts, rec, wrawb, Vb, Ab, N);

    out_mfma_kernel<<<782, 256, 0, stream>>>(Ab, Wb + 3 * 16384, bo, out, N, numTiles);
}

// Round 3
// 247.812 us; speedup vs baseline: 1.1318x; 1.0126x over previous
//
#include <hip/hip_runtime.h>
#include <hip/hip_bf16.h>

// GAT-style graph attention. N=50000, E=600000, FEAT=128, H=8, D=16.
// R12: dispatch-structure round. (a) gather fused with the output GEMM:
//      out = agg @ Wo^T is ROW-LOCAL, so a block gathers 16 nodes' agg rows
//      into LDS (bf16, same rounding as the old agg store) and immediately
//      does its 16x128 MFMA tile — deletes the 25.6MB agg roundtrip and one
//      dispatch. (b) scan3 folded into consumers (offsets[i]+blockoffs[i>>8]).
//      (c) scan2 merged into scan1 via last-block pattern (threadfence
//      release + __hip_atomic_load acquire — XCD-safe); scan1 also zeroes
//      segsum, memset shrinks to counts+done. 10 -> 7 dispatches.
//      Keeps: fill-under-qkv fusion, V pre-scale (absorbs recip), rank-from-
//      histogram CSR, shfl-free sumexp, bf16 wraw.

#define FEAT 128
#define NHEAD 8
#define NPAD 50048   // N rounded up to multiple of 64

typedef __attribute__((ext_vector_type(8))) short bf16x8;
typedef __attribute__((ext_vector_type(4))) float f32x4;

__device__ __forceinline__ unsigned short f2bf(float f) {
    unsigned u = __float_as_uint(f);
    u += 0x7fffu + ((u >> 16) & 1u);
    return (unsigned short)(u >> 16);
}
__device__ __forceinline__ float bf2f_lo(unsigned u) { return __uint_as_float(u << 16); }
__device__ __forceinline__ float bf2f_hi(unsigned u) { return __uint_as_float(u & 0xffff0000u); }
__device__ __forceinline__ float bfw(unsigned short u) { return __uint_as_float((unsigned)u << 16); }

// ---- fused prep: dest histogram (+rank capture) | convert_x | convert_w ----
__global__ __launch_bounds__(256) void prep_kernel(
    const int* __restrict__ dsts, int* __restrict__ counts, int* __restrict__ rank,
    const float* __restrict__ X, unsigned short* __restrict__ Xb, int total8,
    const float* __restrict__ Wq, const float* __restrict__ Wk,
    const float* __restrict__ Wv, const float* __restrict__ Wo,
    unsigned short* __restrict__ Wb,
    int E, int histBlocks, int convxBlocks)
{
    int b = blockIdx.x;
    if (b < histBlocks) {
        int e = b * 256 + threadIdx.x;
        if (e < E) rank[e] = atomicAdd(counts + dsts[e], 1);
        return;
    }
    b -= histBlocks;
    if (b < convxBlocks) {
        int i = b * 256 + threadIdx.x;
        if (i >= total8) return;
        const float4* xp = (const float4*)X + (size_t)i * 2;
        float4 x0 = xp[0], x1 = xp[1];
        uint4 o;
        o.x = (unsigned)f2bf(x0.x) | ((unsigned)f2bf(x0.y) << 16);
        o.y = (unsigned)f2bf(x0.z) | ((unsigned)f2bf(x0.w) << 16);
        o.z = (unsigned)f2bf(x1.x) | ((unsigned)f2bf(x1.y) << 16);
        o.w = (unsigned)f2bf(x1.z) | ((unsigned)f2bf(x1.w) << 16);
        ((uint4*)Xb)[i] = o;
        return;
    }
    b -= convxBlocks;
    int i = b * 256 + threadIdx.x;
    if (i >= 4 * 2048) return;
    int mat = i >> 11, idx = i & 2047;
    const float* W = (mat == 0) ? Wq : (mat == 1) ? Wk : (mat == 2) ? Wv : Wo;
    const float4* xp = (const float4*)W + (size_t)idx * 2;
    float4 x0 = xp[0], x1 = xp[1];
    uint4 o;
    o.x = (unsigned)f2bf(x0.x) | ((unsigned)f2bf(x0.y) << 16);
    o.y = (unsigned)f2bf(x0.z) | ((unsigned)f2bf(x0.w) << 16);
    o.z = (unsigned)f2bf(x1.x) | ((unsigned)f2bf(x1.y) << 16);
    o.w = (unsigned)f2bf(x1.z) | ((unsigned)f2bf(x1.w) << 16);
    ((uint4*)(Wb + (size_t)mat * 16384))[idx] = o;
}

// ---- scan: per-256-block exclusive scan of counts; last block scans the
//      block sums (release: threadfence+atomic; acquire: __hip_atomic_load).
//      Also zeroes segsum (runs before sumexp). Consumers add
//      blockoffs[i>>8] themselves (scan3 folded away). ----
__global__ __launch_bounds__(256) void scan12_kernel(
    const int* __restrict__ counts, int* __restrict__ offsets,
    int* __restrict__ blocksums, int* __restrict__ blockoffs,
    int* __restrict__ done, float4* __restrict__ segsum4,
    int NT, int NB, int NSEG)
{
    __shared__ int buf[256];
    __shared__ int amLast;
    int t = threadIdx.x, b = blockIdx.x;
    int i = b * 256 + t;
    if (i < NSEG) {   // zero segsum: 8 f32 per thread
        float4 z = {0.f, 0.f, 0.f, 0.f};
        segsum4[(size_t)i * 2] = z;
        segsum4[(size_t)i * 2 + 1] = z;
    }
    int v = (i < NT) ? counts[i] : 0;
    buf[t] = v; __syncthreads();
    int x = v;
    #pragma unroll
    for (int off = 1; off < 256; off <<= 1) {
        int y = (t >= off) ? buf[t - off] : 0;
        __syncthreads();
        x += y; buf[t] = x;
        __syncthreads();
    }
    if (i < NT) offsets[i] = x - v;
    if (t == 255) {
        blocksums[b] = x;
        __threadfence();
        amLast = (atomicAdd(done, 1) == (int)gridDim.x - 1);
    }
    __syncthreads();
    if (!amLast) return;
    int v2 = (t < NB)
        ? __hip_atomic_load(&blocksums[t], __ATOMIC_ACQUIRE, __HIP_MEMORY_SCOPE_AGENT)
        : 0;
    buf[t] = v2; __syncthreads();
    int x2 = v2;
    #pragma unroll
    for (int off = 1; off < 256; off <<= 1) {
        int y = (t >= off) ? buf[t - off] : 0;
        __syncthreads();
        x2 += y; buf[t] = x2;
        __syncthreads();
    }
    if (t < NB) blockoffs[t] = x2 - v2;
}

// ---- combined: QKV MFMA GEMM (blocks [0,qkvBlocks)) + dest-CSR fill.
//      Fill is a pure latency-bound scatter (no atomics) hidden under the
//      GEMM. offsets are partial; add blockoffs[d>>8]. ----
__global__ __launch_bounds__(256) void fillqkv_kernel(
    const unsigned short* __restrict__ Xb, const unsigned short* __restrict__ Wb,
    const float* __restrict__ bq, const float* __restrict__ bk, const float* __restrict__ bv,
    unsigned short* __restrict__ Q, unsigned short* __restrict__ K,
    unsigned short* __restrict__ V, int N, int numTiles, int qkvBlocks,
    const int* __restrict__ srcs, const int* __restrict__ dsts,
    const int* __restrict__ rank, const int* __restrict__ offsets,
    const int* __restrict__ blockoffs, int* __restrict__ rec, int E)
{
    if (blockIdx.x >= qkvBlocks) {
        int e = (blockIdx.x - qkvBlocks) * 256 + threadIdx.x;
        if (e < E) {
            int s = srcs[e], d = dsts[e];
            rec[offsets[d] + blockoffs[d >> 8] + rank[e]] = s;
        }
        return;
    }

    const int lane = threadIdx.x & 63;
    const int wave = threadIdx.x >> 6;
    const int m = lane & 15, quad = lane >> 4;
    const int colbase = wave * 32;

    bf16x8 bfr[3][2][4];
    #pragma unroll
    for (int mat = 0; mat < 3; mat++)
        #pragma unroll
        for (int ctl = 0; ctl < 2; ctl++) {
            const unsigned short* wrow =
                Wb + mat * 16384 + (size_t)(colbase + ctl * 16 + m) * FEAT + quad * 8;
            #pragma unroll
            for (int kc = 0; kc < 4; kc++)
                bfr[mat][ctl][kc] = *(const bf16x8*)(wrow + kc * 32);
        }

    const float* bias_p[3] = {bq, bk, bv};
    float bias[3][2];
    #pragma unroll
    for (int mat = 0; mat < 3; mat++)
        #pragma unroll
        for (int ctl = 0; ctl < 2; ctl++)
            bias[mat][ctl] = bias_p[mat][colbase + ctl * 16 + m];

    unsigned short* outp[3] = {Q, K, V};

    for (int tile = blockIdx.x; tile < numTiles; tile += qkvBlocks) {
        const int row0 = tile * 16;
        const unsigned short* arow = Xb + (size_t)(row0 + m) * FEAT + quad * 8;
        bf16x8 a[4];
        #pragma unroll
        for (int kc = 0; kc < 4; kc++) a[kc] = *(const bf16x8*)(arow + kc * 32);
        f32x4 acc[3][2];
        #pragma unroll
        for (int mat = 0; mat < 3; mat++)
            #pragma unroll
            for (int ctl = 0; ctl < 2; ctl++) acc[mat][ctl] = (f32x4){0.f, 0.f, 0.f, 0.f};
        #pragma unroll
        for (int kc = 0; kc < 4; kc++)
            #pragma unroll
            for (int mat = 0; mat < 3; mat++)
                #pragma unroll
                for (int ctl = 0; ctl < 2; ctl++)
                    acc[mat][ctl] = __builtin_amdgcn_mfma_f32_16x16x32_bf16(
                        a[kc], bfr[mat][ctl][kc], acc[mat][ctl], 0, 0, 0);
        #pragma unroll
        for (int mat = 0; mat < 3; mat++)
            #pragma unroll
            for (int ctl = 0; ctl < 2; ctl++)
                #pragma unroll
                for (int reg = 0; reg < 4; reg++) {
                    int row = row0 + quad * 4 + reg;
                    if (row < N)
                        outp[mat][(size_t)row * FEAT + colbase + ctl * 16 + m] =
                            f2bf(acc[mat][ctl][reg] + bias[mat][ctl]);
                }
    }
}

// ---- sumexp: one wave per DEST node, shfl-free. ----
__global__ __launch_bounds__(256) void sumexp_kernel(
    const int* __restrict__ offsets, const int* __restrict__ blockoffs,
    const int* __restrict__ counts, const int* __restrict__ rec,
    const unsigned short* __restrict__ Q, const unsigned short* __restrict__ K,
    unsigned short* __restrict__ wrawb, float* __restrict__ segsum, int N)
{
    int node = blockIdx.x * 4 + (threadIdx.x >> 6);
    if (node >= N) return;
    int lane = threadIdx.x & 63;
    int j = lane >> 3, h = lane & 7;
    int start = offsets[node] + blockoffs[node >> 8];
    int deg = counts[node];
    if (deg == 0) return;

    float kf[16];
    {
        const unsigned* kp = (const unsigned*)(K + (size_t)node * FEAT + h * 16);
        #pragma unroll
        for (int i = 0; i < 8; i++) {
            unsigned u = kp[i];
            kf[2 * i]     = bf2f_lo(u);
            kf[2 * i + 1] = bf2f_hi(u);
        }
    }

    for (int j0 = 0; j0 < deg; j0 += 8) {
        int jj = j0 + j;
        bool act = jj < deg;
        int pos = start + (act ? jj : j0);
        int s = rec[pos];
        const unsigned* qp = (const unsigned*)(Q + (size_t)s * FEAT + h * 16);
        uint4 qa = *(const uint4*)qp;
        uint4 qb = *(const uint4*)(qp + 4);
        float p;
        p  = bf2f_lo(qa.x) * kf[0]  + bf2f_hi(qa.x) * kf[1];
        p += bf2f_lo(qa.y) * kf[2]  + bf2f_hi(qa.y) * kf[3];
        p += bf2f_lo(qa.z) * kf[4]  + bf2f_hi(qa.z) * kf[5];
        p += bf2f_lo(qa.w) * kf[6]  + bf2f_hi(qa.w) * kf[7];
        p += bf2f_lo(qb.x) * kf[8]  + bf2f_hi(qb.x) * kf[9];
        p += bf2f_lo(qb.y) * kf[10] + bf2f_hi(qb.y) * kf[11];
        p += bf2f_lo(qb.z) * kf[12] + bf2f_hi(qb.z) * kf[13];
        p += bf2f_lo(qb.w) * kf[14] + bf2f_hi(qb.w) * kf[15];
        float w = __expf(p * 0.25f);
        if (act) {
            wrawb[(size_t)(start + j0) * NHEAD + lane] = f2bf(w);
            atomicAdd(segsum + (size_t)s * NHEAD + h, w);
        }
    }
}

// ---- scale V in place by 1/segsum per (node, head) ----
__global__ __launch_bounds__(256) void scalev_kernel(
    const float* __restrict__ segsum, unsigned short* __restrict__ V, int total16)
{
    int i = blockIdx.x * 256 + threadIdx.x;
    if (i >= total16) return;
    int s = i >> 4;
    int part = i & 15;
    int h = part >> 1;
    float r = 1.0f / segsum[s * NHEAD + h];
    uint4* p = (uint4*)(V + (size_t)s * FEAT) + part;
    uint4 v = *p;
    uint4 o;
    o.x = (unsigned)f2bf(bf2f_lo(v.x) * r) | ((unsigned)f2bf(bf2f_hi(v.x) * r) << 16);
    o.y = (unsigned)f2bf(bf2f_lo(v.y) * r) | ((unsigned)f2bf(bf2f_hi(v.y) * r) << 16);
    o.z = (unsigned)f2bf(bf2f_lo(v.z) * r) | ((unsigned)f2bf(bf2f_hi(v.z) * r) << 16);
    o.w = (unsigned)f2bf(bf2f_lo(v.w) * r) | ((unsigned)f2bf(bf2f_hi(v.w) * r) << 16);
    *p = o;
}

// ---- fused gather + out GEMM: block owns 16 dest nodes. Phase 1: each
//      wave gathers 4 nodes' agg rows (bf16) into LDS (pitch 136 -> 2-way
//      bank aliasing = free). Phase 2: 16x128 @ Wo^T MFMA tile, f32 out. ----
__global__ __launch_bounds__(256) void gatherout_kernel(
    const int* __restrict__ offsets, const int* __restrict__ blockoffs,
    const int* __restrict__ counts, const int* __restrict__ rec,
    const unsigned short* __restrict__ wrawb, const unsigned short* __restrict__ V,
    const unsigned short* __restrict__ Wob, const float* __restrict__ bo,
    float* __restrict__ out, int N)
{
    __shared__ unsigned short lds[16][136];
    const int wave = threadIdx.x >> 6;
    const int lane = threadIdx.x & 63;
    const int h = lane >> 3;

    for (int i = 0; i < 4; i++) {
        int node = blockIdx.x * 16 + wave * 4 + i;
        float ax = 0.f, ay = 0.f;
        if (node < N) {
            int start = offsets[node] + blockoffs[node >> 8];
            int deg = counts[node];
            int j = 0;
            for (; j + 4 <= deg; j += 4) {
                int p = start + j;
                int s0 = rec[p], s1 = rec[p + 1];
                int s2 = rec[p + 2], s3 = rec[p + 3];
                float w0 = bfw(wrawb[(size_t)(p + 0) * NHEAD + h]);
                float w1 = bfw(wrawb[(size_t)(p + 1) * NHEAD + h]);
                float w2 = bfw(wrawb[(size_t)(p + 2) * NHEAD + h]);
                float w3 = bfw(wrawb[(size_t)(p + 3) * NHEAD + h]);
                unsigned v0 = *(const unsigned*)(V + (size_t)s0 * FEAT + lane * 2);
                unsigned v1 = *(const unsigned*)(V + (size_t)s1 * FEAT + lane * 2);
                unsigned v2 = *(const unsigned*)(V + (size_t)s2 * FEAT + lane * 2);
                unsigned v3 = *(const unsigned*)(V + (size_t)s3 * FEAT + lane * 2);
                ax += w0 * bf2f_lo(v0) + w1 * bf2f_lo(v1) + w2 * bf2f_lo(v2) + w3 * bf2f_lo(v3);
                ay += w0 * bf2f_hi(v0) + w1 * bf2f_hi(v1) + w2 * bf2f_hi(v2) + w3 * bf2f_hi(v3);
            }
            for (; j < deg; j++) {
                int p = start + j;
                int s = rec[p];
                float w = bfw(wrawb[(size_t)p * NHEAD + h]);
                unsigned v = *(const unsigned*)(V + (size_t)s * FEAT + lane * 2);
                ax += w * bf2f_lo(v);
                ay += w * bf2f_hi(v);
            }
        }
        unsigned o = (unsigned)f2bf(ax) | ((unsigned)f2bf(ay) << 16);
        *(unsigned*)&lds[wave * 4 + i][lane * 2] = o;
    }
    __syncthreads();

    const int m = lane & 15, quad = lane >> 4;
    const int colbase = wave * 32;
    bf16x8 a[4];
    #pragma unroll
    for (int kc = 0; kc < 4; kc++)
        a[kc] = *(const bf16x8*)&lds[m][kc * 32 + quad * 8];

    bf16x8 bfr[2][4];
    #pragma unroll
    for (int ctl = 0; ctl < 2; ctl++) {
        const unsigned short* wrow = Wob + (size_t)(colbase + ctl * 16 + m) * FEAT + quad * 8;
        #pragma unroll
        for (int kc = 0; kc < 4; kc++)
            bfr[ctl][kc] = *(const bf16x8*)(wrow + kc * 32);
    }
    float bias[2];
    #pragma unroll
    for (int ctl = 0; ctl < 2; ctl++) bias[ctl] = bo[colbase + ctl * 16 + m];

    f32x4 acc[2];
    #pragma unroll
    for (int ctl = 0; ctl < 2; ctl++) acc[ctl] = (f32x4){0.f, 0.f, 0.f, 0.f};
    #pragma unroll
    for (int kc = 0; kc < 4; kc++)
        #pragma unroll
        for (int ctl = 0; ctl < 2; ctl++)
            acc[ctl] = __builtin_amdgcn_mfma_f32_16x16x32_bf16(
                a[kc], bfr[ctl][kc], acc[ctl], 0, 0, 0);

    const int row0 = blockIdx.x * 16;
    #pragma unroll
    for (int ctl = 0; ctl < 2; ctl++)
        #pragma unroll
        for (int reg = 0; reg < 4; reg++) {
            int row = row0 + quad * 4 + reg;
            if (row < N)
                out[(size_t)row * FEAT + colbase + ctl * 16 + m] = acc[ctl][reg] + bias[ctl];
        }
}

extern "C" void kernel_launch(void* const* d_in, const int* in_sizes, int n_in,
                              void* d_out, int out_size, void* d_ws, size_t ws_size,
                              hipStream_t stream) {
    const float* X  = (const float*)d_in[0];
    const int*   ei = (const int*)d_in[1];
    const float* Wq = (const float*)d_in[2];
    const float* bq = (const float*)d_in[3];
    const float* Wk = (const float*)d_in[4];
    const float* bk = (const float*)d_in[5];
    const float* Wv = (const float*)d_in[6];
    const float* bv = (const float*)d_in[7];
    const float* Wo = (const float*)d_in[8];
    const float* bo = (const float*)d_in[9];
    float* out = (float*)d_out;

    const int N = in_sizes[0] / FEAT;        // 50000
    const int E = in_sizes[1] / 2;           // 600000
    const int* srcs = ei;
    const int* dsts = ei + E;
    const size_t NF2 = (size_t)NPAD * FEAT * 2;

    char* w = (char*)d_ws;
    unsigned short* Xb = (unsigned short*)w;  w += NF2;
    unsigned short* Qb = (unsigned short*)w;  w += NF2;
    unsigned short* Kb = (unsigned short*)w;  w += NF2;
    unsigned short* Vb = (unsigned short*)w;  w += NF2;
    unsigned short* Wb = (unsigned short*)w;  w += (size_t)4 * 16384 * 2;
    unsigned short* wrawb = (unsigned short*)w; w += (size_t)E * NHEAD * 2;  // bf16
    float* segsum      = (float*)w;           w += (size_t)N * NHEAD * 4;  // zeroed by scan12
    int* counts        = (int*)w;             w += (size_t)N * 4;          // zeroed (memset)
    int* done          = (int*)w;             w += 16;                      // zeroed (memset)
    int* offsets       = (int*)w;             w += (size_t)N * 4;
    int* blocksums     = (int*)w;             w += 256 * 4;
    int* blockoffs     = (int*)w;             w += 256 * 4;
    int* rec           = (int*)w;             w += (size_t)E * 4;
    int* rank          = (int*)w;             w += (size_t)E * 4;

    // zero counts + done (contiguous)
    hipMemsetAsync(counts, 0, (size_t)N * 4 + 16, stream);

    int e_blocks = (E + 255) / 256;          // 2344
    int x8 = N * FEAT / 8;
    int convx_blocks = (x8 + 255) / 256;     // 3125
    int convw_blocks = 32;
    prep_kernel<<<e_blocks + convx_blocks + convw_blocks, 256, 0, stream>>>(
        dsts, counts, rank, X, Xb, x8, Wq, Wk, Wv, Wo, Wb,
        E, e_blocks, convx_blocks);

    int NB = (N + 255) / 256;   // 196
    scan12_kernel<<<NB, 256, 0, stream>>>(
        counts, offsets, blocksums, blockoffs, done, (float4*)segsum, N, NB, N);

    int numTiles = NPAD / 16;   // 3128
    int qkvBlocks = 782;
    fillqkv_kernel<<<qkvBlocks + e_blocks, 256, 0, stream>>>(
        Xb, Wb, bq, bk, bv, Qb, Kb, Vb, N, numTiles, qkvBlocks,
        srcs, dsts, rank, offsets, blockoffs, rec, E);

    int node_blocks = (N + 3) / 4;
    sumexp_kernel<<<node_blocks, 256, 0, stream>>>(
        offsets, blockoffs, counts, rec, Qb, Kb, wrawb, segsum, N);

    scalev_kernel<<<(N * 16 + 255) / 256, 256, 0, stream>>>(segsum, Vb, N * 16);

    gatherout_kernel<<<(N + 15) / 16, 256, 0, stream>>>(
        offsets, blockoffs, counts, rec, wrawb, Vb, Wb + 3 * 16384, bo, out, N);
}

// Round 4
// 244.312 us; speedup vs baseline: 1.1480x; 1.0143x over previous
//
#include <hip/hip_runtime.h>
#include <hip/hip_bf16.h>

// GAT-style graph attention. N=50000, E=600000, FEAT=128, H=8, D=16.
// R13: gather phase restructured for memory-level parallelism. R12 counters
//      showed gatherout = 50µs latency-bound (Mfma 1%, VALU 27%, HBM 23%,
//      occ 55%): one edge per vmem instruction (64 lanes x 4B on one V row),
//      only 4 edges in flight. Now lane=(edge-slot j=lane>>3, head h=lane&7)
//      like sumexp: one instruction covers 8 edges (2x uint4 per lane,
//      acc[16] f32/lane), then a 3-level shfl_xor(8/16/32) butterfly over the
//      j-bits reduces edge-slots; j==0 lanes pack bf16 into the LDS tile for
//      the fused 16x128 MFMA @ Wo^T. ~6x fewer vmem instructions, 2x+ edges
//      in flight. Everything else unchanged from R12.

#define FEAT 128
#define NHEAD 8
#define NPAD 50048   // N rounded up to multiple of 64

typedef __attribute__((ext_vector_type(8))) short bf16x8;
typedef __attribute__((ext_vector_type(4))) float f32x4;

__device__ __forceinline__ unsigned short f2bf(float f) {
    unsigned u = __float_as_uint(f);
    u += 0x7fffu + ((u >> 16) & 1u);
    return (unsigned short)(u >> 16);
}
__device__ __forceinline__ float bf2f_lo(unsigned u) { return __uint_as_float(u << 16); }
__device__ __forceinline__ float bf2f_hi(unsigned u) { return __uint_as_float(u & 0xffff0000u); }
__device__ __forceinline__ float bfw(unsigned short u) { return __uint_as_float((unsigned)u << 16); }

// ---- fused prep: dest histogram (+rank capture) | convert_x | convert_w ----
__global__ __launch_bounds__(256) void prep_kernel(
    const int* __restrict__ dsts, int* __restrict__ counts, int* __restrict__ rank,
    const float* __restrict__ X, unsigned short* __restrict__ Xb, int total8,
    const float* __restrict__ Wq, const float* __restrict__ Wk,
    const float* __restrict__ Wv, const float* __restrict__ Wo,
    unsigned short* __restrict__ Wb,
    int E, int histBlocks, int convxBlocks)
{
    int b = blockIdx.x;
    if (b < histBlocks) {
        int e = b * 256 + threadIdx.x;
        if (e < E) rank[e] = atomicAdd(counts + dsts[e], 1);
        return;
    }
    b -= histBlocks;
    if (b < convxBlocks) {
        int i = b * 256 + threadIdx.x;
        if (i >= total8) return;
        const float4* xp = (const float4*)X + (size_t)i * 2;
        float4 x0 = xp[0], x1 = xp[1];
        uint4 o;
        o.x = (unsigned)f2bf(x0.x) | ((unsigned)f2bf(x0.y) << 16);
        o.y = (unsigned)f2bf(x0.z) | ((unsigned)f2bf(x0.w) << 16);
        o.z = (unsigned)f2bf(x1.x) | ((unsigned)f2bf(x1.y) << 16);
        o.w = (unsigned)f2bf(x1.z) | ((unsigned)f2bf(x1.w) << 16);
        ((uint4*)Xb)[i] = o;
        return;
    }
    b -= convxBlocks;
    int i = b * 256 + threadIdx.x;
    if (i >= 4 * 2048) return;
    int mat = i >> 11, idx = i & 2047;
    const float* W = (mat == 0) ? Wq : (mat == 1) ? Wk : (mat == 2) ? Wv : Wo;
    const float4* xp = (const float4*)W + (size_t)idx * 2;
    float4 x0 = xp[0], x1 = xp[1];
    uint4 o;
    o.x = (unsigned)f2bf(x0.x) | ((unsigned)f2bf(x0.y) << 16);
    o.y = (unsigned)f2bf(x0.z) | ((unsigned)f2bf(x0.w) << 16);
    o.z = (unsigned)f2bf(x1.x) | ((unsigned)f2bf(x1.y) << 16);
    o.w = (unsigned)f2bf(x1.z) | ((unsigned)f2bf(x1.w) << 16);
    ((uint4*)(Wb + (size_t)mat * 16384))[idx] = o;
}

// ---- scan: per-256-block exclusive scan of counts; last block scans the
//      block sums. Also zeroes segsum. Consumers add blockoffs[i>>8]. ----
__global__ __launch_bounds__(256) void scan12_kernel(
    const int* __restrict__ counts, int* __restrict__ offsets,
    int* __restrict__ blocksums, int* __restrict__ blockoffs,
    int* __restrict__ done, float4* __restrict__ segsum4,
    int NT, int NB, int NSEG)
{
    __shared__ int buf[256];
    __shared__ int amLast;
    int t = threadIdx.x, b = blockIdx.x;
    int i = b * 256 + t;
    if (i < NSEG) {   // zero segsum: 8 f32 per thread
        float4 z = {0.f, 0.f, 0.f, 0.f};
        segsum4[(size_t)i * 2] = z;
        segsum4[(size_t)i * 2 + 1] = z;
    }
    int v = (i < NT) ? counts[i] : 0;
    buf[t] = v; __syncthreads();
    int x = v;
    #pragma unroll
    for (int off = 1; off < 256; off <<= 1) {
        int y = (t >= off) ? buf[t - off] : 0;
        __syncthreads();
        x += y; buf[t] = x;
        __syncthreads();
    }
    if (i < NT) offsets[i] = x - v;
    if (t == 255) {
        blocksums[b] = x;
        __threadfence();
        amLast = (atomicAdd(done, 1) == (int)gridDim.x - 1);
    }
    __syncthreads();
    if (!amLast) return;
    int v2 = (t < NB)
        ? __hip_atomic_load(&blocksums[t], __ATOMIC_ACQUIRE, __HIP_MEMORY_SCOPE_AGENT)
        : 0;
    buf[t] = v2; __syncthreads();
    int x2 = v2;
    #pragma unroll
    for (int off = 1; off < 256; off <<= 1) {
        int y = (t >= off) ? buf[t - off] : 0;
        __syncthreads();
        x2 += y; buf[t] = x2;
        __syncthreads();
    }
    if (t < NB) blockoffs[t] = x2 - v2;
}

// ---- combined: QKV MFMA GEMM + dest-CSR fill (hidden under the GEMM) ----
__global__ __launch_bounds__(256) void fillqkv_kernel(
    const unsigned short* __restrict__ Xb, const unsigned short* __restrict__ Wb,
    const float* __restrict__ bq, const float* __restrict__ bk, const float* __restrict__ bv,
    unsigned short* __restrict__ Q, unsigned short* __restrict__ K,
    unsigned short* __restrict__ V, int N, int numTiles, int qkvBlocks,
    const int* __restrict__ srcs, const int* __restrict__ dsts,
    const int* __restrict__ rank, const int* __restrict__ offsets,
    const int* __restrict__ blockoffs, int* __restrict__ rec, int E)
{
    if (blockIdx.x >= qkvBlocks) {
        int e = (blockIdx.x - qkvBlocks) * 256 + threadIdx.x;
        if (e < E) {
            int s = srcs[e], d = dsts[e];
            rec[offsets[d] + blockoffs[d >> 8] + rank[e]] = s;
        }
        return;
    }

    const int lane = threadIdx.x & 63;
    const int wave = threadIdx.x >> 6;
    const int m = lane & 15, quad = lane >> 4;
    const int colbase = wave * 32;

    bf16x8 bfr[3][2][4];
    #pragma unroll
    for (int mat = 0; mat < 3; mat++)
        #pragma unroll
        for (int ctl = 0; ctl < 2; ctl++) {
            const unsigned short* wrow =
                Wb + mat * 16384 + (size_t)(colbase + ctl * 16 + m) * FEAT + quad * 8;
            #pragma unroll
            for (int kc = 0; kc < 4; kc++)
                bfr[mat][ctl][kc] = *(const bf16x8*)(wrow + kc * 32);
        }

    const float* bias_p[3] = {bq, bk, bv};
    float bias[3][2];
    #pragma unroll
    for (int mat = 0; mat < 3; mat++)
        #pragma unroll
        for (int ctl = 0; ctl < 2; ctl++)
            bias[mat][ctl] = bias_p[mat][colbase + ctl * 16 + m];

    unsigned short* outp[3] = {Q, K, V};

    for (int tile = blockIdx.x; tile < numTiles; tile += qkvBlocks) {
        const int row0 = tile * 16;
        const unsigned short* arow = Xb + (size_t)(row0 + m) * FEAT + quad * 8;
        bf16x8 a[4];
        #pragma unroll
        for (int kc = 0; kc < 4; kc++) a[kc] = *(const bf16x8*)(arow + kc * 32);
        f32x4 acc[3][2];
        #pragma unroll
        for (int mat = 0; mat < 3; mat++)
            #pragma unroll
            for (int ctl = 0; ctl < 2; ctl++) acc[mat][ctl] = (f32x4){0.f, 0.f, 0.f, 0.f};
        #pragma unroll
        for (int kc = 0; kc < 4; kc++)
            #pragma unroll
            for (int mat = 0; mat < 3; mat++)
                #pragma unroll
                for (int ctl = 0; ctl < 2; ctl++)
                    acc[mat][ctl] = __builtin_amdgcn_mfma_f32_16x16x32_bf16(
                        a[kc], bfr[mat][ctl][kc], acc[mat][ctl], 0, 0, 0);
        #pragma unroll
        for (int mat = 0; mat < 3; mat++)
            #pragma unroll
            for (int ctl = 0; ctl < 2; ctl++)
                #pragma unroll
                for (int reg = 0; reg < 4; reg++) {
                    int row = row0 + quad * 4 + reg;
                    if (row < N)
                        outp[mat][(size_t)row * FEAT + colbase + ctl * 16 + m] =
                            f2bf(acc[mat][ctl][reg] + bias[mat][ctl]);
                }
    }
}

// ---- sumexp: one wave per DEST node, shfl-free. ----
__global__ __launch_bounds__(256) void sumexp_kernel(
    const int* __restrict__ offsets, const int* __restrict__ blockoffs,
    const int* __restrict__ counts, const int* __restrict__ rec,
    const unsigned short* __restrict__ Q, const unsigned short* __restrict__ K,
    unsigned short* __restrict__ wrawb, float* __restrict__ segsum, int N)
{
    int node = blockIdx.x * 4 + (threadIdx.x >> 6);
    if (node >= N) return;
    int lane = threadIdx.x & 63;
    int j = lane >> 3, h = lane & 7;
    int start = offsets[node] + blockoffs[node >> 8];
    int deg = counts[node];
    if (deg == 0) return;

    float kf[16];
    {
        const unsigned* kp = (const unsigned*)(K + (size_t)node * FEAT + h * 16);
        #pragma unroll
        for (int i = 0; i < 8; i++) {
            unsigned u = kp[i];
            kf[2 * i]     = bf2f_lo(u);
            kf[2 * i + 1] = bf2f_hi(u);
        }
    }

    for (int j0 = 0; j0 < deg; j0 += 8) {
        int jj = j0 + j;
        bool act = jj < deg;
        int pos = start + (act ? jj : j0);
        int s = rec[pos];
        const unsigned* qp = (const unsigned*)(Q + (size_t)s * FEAT + h * 16);
        uint4 qa = *(const uint4*)qp;
        uint4 qb = *(const uint4*)(qp + 4);
        float p;
        p  = bf2f_lo(qa.x) * kf[0]  + bf2f_hi(qa.x) * kf[1];
        p += bf2f_lo(qa.y) * kf[2]  + bf2f_hi(qa.y) * kf[3];
        p += bf2f_lo(qa.z) * kf[4]  + bf2f_hi(qa.z) * kf[5];
        p += bf2f_lo(qa.w) * kf[6]  + bf2f_hi(qa.w) * kf[7];
        p += bf2f_lo(qb.x) * kf[8]  + bf2f_hi(qb.x) * kf[9];
        p += bf2f_lo(qb.y) * kf[10] + bf2f_hi(qb.y) * kf[11];
        p += bf2f_lo(qb.z) * kf[12] + bf2f_hi(qb.z) * kf[13];
        p += bf2f_lo(qb.w) * kf[14] + bf2f_hi(qb.w) * kf[15];
        float w = __expf(p * 0.25f);
        if (act) {
            wrawb[(size_t)(start + j0) * NHEAD + lane] = f2bf(w);
            atomicAdd(segsum + (size_t)s * NHEAD + h, w);
        }
    }
}

// ---- scale V in place by 1/segsum per (node, head) ----
__global__ __launch_bounds__(256) void scalev_kernel(
    const float* __restrict__ segsum, unsigned short* __restrict__ V, int total16)
{
    int i = blockIdx.x * 256 + threadIdx.x;
    if (i >= total16) return;
    int s = i >> 4;
    int part = i & 15;
    int h = part >> 1;
    float r = 1.0f / segsum[s * NHEAD + h];
    uint4* p = (uint4*)(V + (size_t)s * FEAT) + part;
    uint4 v = *p;
    uint4 o;
    o.x = (unsigned)f2bf(bf2f_lo(v.x) * r) | ((unsigned)f2bf(bf2f_hi(v.x) * r) << 16);
    o.y = (unsigned)f2bf(bf2f_lo(v.y) * r) | ((unsigned)f2bf(bf2f_hi(v.y) * r) << 16);
    o.z = (unsigned)f2bf(bf2f_lo(v.z) * r) | ((unsigned)f2bf(bf2f_hi(v.z) * r) << 16);
    o.w = (unsigned)f2bf(bf2f_lo(v.w) * r) | ((unsigned)f2bf(bf2f_hi(v.w) * r) << 16);
    *p = o;
}

// ---- fused gather + out GEMM: block owns 16 dest nodes.
//      Phase 1 (MLP-restructured): lane = (edge-slot j=lane>>3, head
//      h=lane&7); each lane accumulates head h's 16 dims over its stride-8
//      edge subset (2x uint4 V loads per edge -> 8 edges per instruction),
//      then shfl_xor(8/16/32) reduces edge-slots; j==0 lanes pack bf16 into
//      LDS (pitch 136). Phase 2: 16x128 @ Wo^T MFMA tile, f32 out. ----
__global__ __launch_bounds__(256) void gatherout_kernel(
    const int* __restrict__ offsets, const int* __restrict__ blockoffs,
    const int* __restrict__ counts, const int* __restrict__ rec,
    const unsigned short* __restrict__ wrawb, const unsigned short* __restrict__ V,
    const unsigned short* __restrict__ Wob, const float* __restrict__ bo,
    float* __restrict__ out, int N)
{
    __shared__ unsigned short lds[16][136];
    const int wave = threadIdx.x >> 6;
    const int lane = threadIdx.x & 63;
    const int j = lane >> 3, h = lane & 7;

    for (int i = 0; i < 4; i++) {
        int node = blockIdx.x * 16 + wave * 4 + i;
        float acc[16];
        #pragma unroll
        for (int d = 0; d < 16; d++) acc[d] = 0.f;
        if (node < N) {
            int start = offsets[node] + blockoffs[node >> 8];
            int deg = counts[node];
            for (int j0 = 0; j0 < deg; j0 += 8) {
                int jj = j0 + j;
                bool act = jj < deg;
                int pos = start + (act ? jj : j0);
                int s = rec[pos];
                float w = act ? bfw(wrawb[(size_t)pos * NHEAD + h]) : 0.f;
                const uint4* vp = (const uint4*)(V + (size_t)s * FEAT + h * 16);
                uint4 va = vp[0], vb = vp[1];
                acc[0]  += w * bf2f_lo(va.x); acc[1]  += w * bf2f_hi(va.x);
                acc[2]  += w * bf2f_lo(va.y); acc[3]  += w * bf2f_hi(va.y);
                acc[4]  += w * bf2f_lo(va.z); acc[5]  += w * bf2f_hi(va.z);
                acc[6]  += w * bf2f_lo(va.w); acc[7]  += w * bf2f_hi(va.w);
                acc[8]  += w * bf2f_lo(vb.x); acc[9]  += w * bf2f_hi(vb.x);
                acc[10] += w * bf2f_lo(vb.y); acc[11] += w * bf2f_hi(vb.y);
                acc[12] += w * bf2f_lo(vb.z); acc[13] += w * bf2f_hi(vb.z);
                acc[14] += w * bf2f_lo(vb.w); acc[15] += w * bf2f_hi(vb.w);
            }
        }
        // butterfly reduce over edge-slot bits (lane bits 3..5)
        #pragma unroll
        for (int mask = 8; mask <= 32; mask <<= 1)
            #pragma unroll
            for (int d = 0; d < 16; d++)
                acc[d] += __shfl_xor(acc[d], mask, 64);
        if (j == 0) {
            unsigned* dst = (unsigned*)&lds[wave * 4 + i][h * 16];
            #pragma unroll
            for (int d = 0; d < 8; d++)
                dst[d] = (unsigned)f2bf(acc[2 * d]) | ((unsigned)f2bf(acc[2 * d + 1]) << 16);
        }
    }
    __syncthreads();

    const int m = lane & 15, quad = lane >> 4;
    const int colbase = wave * 32;
    bf16x8 a[4];
    #pragma unroll
    for (int kc = 0; kc < 4; kc++)
        a[kc] = *(const bf16x8*)&lds[m][kc * 32 + quad * 8];

    bf16x8 bfr[2][4];
    #pragma unroll
    for (int ctl = 0; ctl < 2; ctl++) {
        const unsigned short* wrow = Wob + (size_t)(colbase + ctl * 16 + m) * FEAT + quad * 8;
        #pragma unroll
        for (int kc = 0; kc < 4; kc++)
            bfr[ctl][kc] = *(const bf16x8*)(wrow + kc * 32);
    }
    float bias[2];
    #pragma unroll
    for (int ctl = 0; ctl < 2; ctl++) bias[ctl] = bo[colbase + ctl * 16 + m];

    f32x4 acc2[2];
    #pragma unroll
    for (int ctl = 0; ctl < 2; ctl++) acc2[ctl] = (f32x4){0.f, 0.f, 0.f, 0.f};
    #pragma unroll
    for (int kc = 0; kc < 4; kc++)
        #pragma unroll
        for (int ctl = 0; ctl < 2; ctl++)
            acc2[ctl] = __builtin_amdgcn_mfma_f32_16x16x32_bf16(
                a[kc], bfr[ctl][kc], acc2[ctl], 0, 0, 0);

    const int row0 = blockIdx.x * 16;
    #pragma unroll
    for (int ctl = 0; ctl < 2; ctl++)
        #pragma unroll
        for (int reg = 0; reg < 4; reg++) {
            int row = row0 + quad * 4 + reg;
            if (row < N)
                out[(size_t)row * FEAT + colbase + ctl * 16 + m] = acc2[ctl][reg] + bias[ctl];
        }
}

extern "C" void kernel_launch(void* const* d_in, const int* in_sizes, int n_in,
                              void* d_out, int out_size, void* d_ws, size_t ws_size,
                              hipStream_t stream) {
    const float* X  = (const float*)d_in[0];
    const int*   ei = (const int*)d_in[1];
    const float* Wq = (const float*)d_in[2];
    const float* bq = (const float*)d_in[3];
    const float* Wk = (const float*)d_in[4];
    const float* bk = (const float*)d_in[5];
    const float* Wv = (const float*)d_in[6];
    const float* bv = (const float*)d_in[7];
    const float* Wo = (const float*)d_in[8];
    const float* bo = (const float*)d_in[9];
    float* out = (float*)d_out;

    const int N = in_sizes[0] / FEAT;        // 50000
    const int E = in_sizes[1] / 2;           // 600000
    const int* srcs = ei;
    const int* dsts = ei + E;
    const size_t NF2 = (size_t)NPAD * FEAT * 2;

    char* w = (char*)d_ws;
    unsigned short* Xb = (unsigned short*)w;  w += NF2;
    unsigned short* Qb = (unsigned short*)w;  w += NF2;
    unsigned short* Kb = (unsigned short*)w;  w += NF2;
    unsigned short* Vb = (unsigned short*)w;  w += NF2;
    unsigned short* Wb = (unsigned short*)w;  w += (size_t)4 * 16384 * 2;
    unsigned short* wrawb = (unsigned short*)w; w += (size_t)E * NHEAD * 2;  // bf16
    float* segsum      = (float*)w;           w += (size_t)N * NHEAD * 4;  // zeroed by scan12
    int* counts        = (int*)w;             w += (size_t)N * 4;          // zeroed (memset)
    int* done          = (int*)w;             w += 16;                      // zeroed (memset)
    int* offsets       = (int*)w;             w += (size_t)N * 4;
    int* blocksums     = (int*)w;             w += 256 * 4;
    int* blockoffs     = (int*)w;             w += 256 * 4;
    int* rec           = (int*)w;             w += (size_t)E * 4;
    int* rank          = (int*)w;             w += (size_t)E * 4;

    // zero counts + done (contiguous)
    hipMemsetAsync(counts, 0, (size_t)N * 4 + 16, stream);

    int e_blocks = (E + 255) / 256;          // 2344
    int x8 = N * FEAT / 8;
    int convx_blocks = (x8 + 255) / 256;     // 3125
    int convw_blocks = 32;
    prep_kernel<<<e_blocks + convx_blocks + convw_blocks, 256, 0, stream>>>(
        dsts, counts, rank, X, Xb, x8, Wq, Wk, Wv, Wo, Wb,
        E, e_blocks, convx_blocks);

    int NB = (N + 255) / 256;   // 196
    scan12_kernel<<<NB, 256, 0, stream>>>(
        counts, offsets, blocksums, blockoffs, done, (float4*)segsum, N, NB, N);

    int numTiles = NPAD / 16;   // 3128
    int qkvBlocks = 782;
    fillqkv_kernel<<<qkvBlocks + e_blocks, 256, 0, stream>>>(
        Xb, Wb, bq, bk, bv, Qb, Kb, Vb, N, numTiles, qkvBlocks,
        srcs, dsts, rank, offsets, blockoffs, rec, E);

    int node_blocks = (N + 3) / 4;
    sumexp_kernel<<<node_blocks, 256, 0, stream>>>(
        offsets, blockoffs, counts, rec, Qb, Kb, wrawb, segsum, N);

    scalev_kernel<<<(N * 16 + 255) / 256, 256, 0, stream>>>(segsum, Vb, N * 16);

    gatherout_kernel<<<(N + 15) / 16, 256, 0, stream>>>(
        offsets, blockoffs, counts, rec, wrawb, Vb, Wb + 3 * 16384, bo, out, N);
}